// Round 2
// baseline (169.812 us; speedup 1.0000x reference)
//
#include <hip/hip_runtime.h>

#define HDIM 1024
#define NW 18            // 6 gate rows + 12 expert rows (e*2+l)
#define ROWS_PER_BLOCK 128
#define NTHREADS 256

typedef float f32x4 __attribute__((ext_vector_type(4)));

// Structure:
//  - No LDS. Weights (72 KB total) are read via global loads; the 16 clusters of a
//    wave broadcast the same 4 addresses, so each weight load coalesces to ONE
//    fully-used 64B segment and hits L1/L2.
//  - x (cls) mapping: 4-lane cluster, INTERLEAVED columns: lane c reads
//    cols j*16 + c*4 .. +4  -> each cluster load is 64B contiguous; every byte
//    consumed exactly once -> nontemporal loads (don't pollute L2).
//  - R=2 rows per lane (rows s and s+16 of the wave's 32-row group).
__global__ __launch_bounds__(NTHREADS, 2)
void hardmoe_kernel(const float* __restrict__ cls,
                    const float* __restrict__ gate_w,
                    const float* __restrict__ gate_b,
                    const float* __restrict__ expert_w,
                    const float* __restrict__ expert_b,
                    float* __restrict__ out, int B)
{
    const int t  = threadIdx.x;
    const int wv = t >> 6;       // wave 0..3
    const int l  = t & 63;
    const int s  = l >> 2;       // row slot 0..15
    const int c  = l & 3;        // col interleave 0..3

    const int rowbase = blockIdx.x * ROWS_PER_BLOCK + wv * 32;
    const int row0 = rowbase + s;
    const int row1 = rowbase + s + 16;
    const int r0c = row0 < B ? row0 : B - 1;
    const int r1c = row1 < B ? row1 : B - 1;

    const float* p0 = cls + (size_t)r0c * HDIM + c * 4;
    const float* p1 = cls + (size_t)r1c * HDIM + c * 4;

    float a0[NW], a1[NW];
#pragma unroll
    for (int w = 0; w < NW; ++w) { a0[w] = 0.f; a1[w] = 0.f; }

#pragma unroll 4
    for (int j = 0; j < 64; ++j) {
        f32x4 x0 = __builtin_nontemporal_load(reinterpret_cast<const f32x4*>(p0) + (size_t)j * 4);
        f32x4 x1 = __builtin_nontemporal_load(reinterpret_cast<const f32x4*>(p1) + (size_t)j * 4);
#pragma unroll
        for (int w = 0; w < NW; ++w) {
            const float* wbase = (w < 6) ? (gate_w + (size_t)w * HDIM)
                                         : (expert_w + (size_t)(w - 6) * HDIM);
            f32x4 wf = *(reinterpret_cast<const f32x4*>(wbase + c * 4) + (size_t)j * 4);
            float t0 = a0[w];
            t0 = fmaf(x0.x, wf.x, t0);
            t0 = fmaf(x0.y, wf.y, t0);
            t0 = fmaf(x0.z, wf.z, t0);
            t0 = fmaf(x0.w, wf.w, t0);
            a0[w] = t0;
            float t1 = a1[w];
            t1 = fmaf(x1.x, wf.x, t1);
            t1 = fmaf(x1.y, wf.y, t1);
            t1 = fmaf(x1.z, wf.z, t1);
            t1 = fmaf(x1.w, wf.w, t1);
            a1[w] = t1;
        }
    }

    // ---- Reduce across the 4-lane cluster (c dimension): xor 1, xor 2 ----
#pragma unroll
    for (int w = 0; w < NW; ++w) {
        a0[w] += __shfl_xor(a0[w], 1);
        a0[w] += __shfl_xor(a0[w], 2);
        a1[w] += __shfl_xor(a1[w], 1);
        a1[w] += __shfl_xor(a1[w], 2);
    }

    // ---- Biases (uniform -> scalar loads) ----
    float gb[6], eb[12];
#pragma unroll
    for (int e = 0; e < 6; ++e) gb[e] = gate_b[e];
#pragma unroll
    for (int k = 0; k < 12; ++k) eb[k] = expert_b[k];

    // ---- Gate argmax (strict >, first-max tiebreak = jnp.argmax) + select ----
    {
        float best = a0[0] + gb[0];
        int idx = 0;
#pragma unroll
        for (int e = 1; e < 6; ++e) {
            float v = a0[e] + gb[e];
            if (v > best) { best = v; idx = e; }
        }
        float o0 = 0.f, o1 = 0.f;
#pragma unroll
        for (int e = 0; e < 6; ++e) {
            bool m = (idx == e);
            o0 = m ? (a0[6 + 2 * e] + eb[2 * e])     : o0;
            o1 = m ? (a0[7 + 2 * e] + eb[2 * e + 1]) : o1;
        }
        if (c == 0 && row0 < B)
            *reinterpret_cast<float2*>(out + (size_t)row0 * 2) = make_float2(o0, o1);
    }
    {
        float best = a1[0] + gb[0];
        int idx = 0;
#pragma unroll
        for (int e = 1; e < 6; ++e) {
            float v = a1[e] + gb[e];
            if (v > best) { best = v; idx = e; }
        }
        float o0 = 0.f, o1 = 0.f;
#pragma unroll
        for (int e = 0; e < 6; ++e) {
            bool m = (idx == e);
            o0 = m ? (a1[6 + 2 * e] + eb[2 * e])     : o0;
            o1 = m ? (a1[7 + 2 * e] + eb[2 * e + 1]) : o1;
        }
        if (c == 0 && row1 < B)
            *reinterpret_cast<float2*>(out + (size_t)row1 * 2) = make_float2(o0, o1);
    }
}

extern "C" void kernel_launch(void* const* d_in, const int* in_sizes, int n_in,
                              void* d_out, int out_size, void* d_ws, size_t ws_size,
                              hipStream_t stream) {
    const float* cls      = (const float*)d_in[0];
    const float* gate_w   = (const float*)d_in[1];
    const float* gate_b   = (const float*)d_in[2];
    const float* expert_w = (const float*)d_in[3];
    const float* expert_b = (const float*)d_in[4];
    float* out = (float*)d_out;

    const int B = in_sizes[0] / HDIM;
    const int grid = (B + ROWS_PER_BLOCK - 1) / ROWS_PER_BLOCK;

    hardmoe_kernel<<<grid, NTHREADS, 0, stream>>>(cls, gate_w, gate_b,
                                                  expert_w, expert_b, out, B);
}

// Round 3
// 64.892 us; speedup vs baseline: 2.6168x; 2.6168x over previous
//
#include <hip/hip_runtime.h>

#define HDIM 1024
#define NW 18            // 6 gate rows + 12 expert rows (e*2+l)
#define NTHREADS 256
#define ROWS_PER_BLOCK 256   // 4 waves x 64 rows

typedef float f32x4 __attribute__((ext_vector_type(4)));

// Structure (R3):
//  - Weights (72 KB) staged once into LDS, interleaved [slot s=0..255][w=0..17] f32x4
//    so each j-iteration is ONE lane address + 18 ds_read_b128 with immediate offsets.
//  - Wave = 8 clusters x 8 lanes. Lane (s8,c): cluster s8, col sublane c.
//    Per j (32 iters), cluster reads cols [32j, 32j+32) = 128B contiguous (full line).
//  - R=8 rows per lane (rows wavebase + k*8 + s8, k=0..7): the 18 LDS reads/j are
//    amortized over 8 rows; acc[8][18] lives in VGPRs (~240 total, 1 wave/SIMD OK).
//  - Explicit 2-deep static double-buffer (xA/xB) for the x stream -> 8 nontemporal
//    16B loads in flight per wave; weights stay hot in L2, x bypasses it.
__global__ __launch_bounds__(NTHREADS, 1)
void hardmoe_kernel(const float* __restrict__ cls,
                    const float* __restrict__ gate_w,
                    const float* __restrict__ gate_b,
                    const float* __restrict__ expert_w,
                    const float* __restrict__ expert_b,
                    float* __restrict__ out, int B)
{
    __shared__ f32x4 Wl[256 * NW];   // 72 KB

    const int t = threadIdx.x;

    // ---- Stage weights: thread t owns f4-slot s=t for all 18 w (coalesced reads) ----
    {
        const int s = t;
#pragma unroll
        for (int w = 0; w < NW; ++w) {
            const float* src = (w < 6) ? (gate_w + (size_t)w * HDIM)
                                       : (expert_w + (size_t)(w - 6) * HDIM);
            Wl[s * NW + w] = *(reinterpret_cast<const f32x4*>(src) + s);
        }
    }

    // ---- Biases (uniform -> scalar loads) ----
    float gb[6], eb[12];
#pragma unroll
    for (int e = 0; e < 6; ++e) gb[e] = gate_b[e];
#pragma unroll
    for (int k = 0; k < 12; ++k) eb[k] = expert_b[k];

    __syncthreads();

    const int wv = t >> 6;       // wave 0..3
    const int l  = t & 63;
    const int s8 = l >> 3;       // cluster 0..7
    const int c  = l & 7;        // col sublane 0..7

    const int wavebase = blockIdx.x * ROWS_PER_BLOCK + wv * 64;

    // 8 row pointers (clamped)
    const float* px[8];
    int rows[8];
#pragma unroll
    for (int k = 0; k < 8; ++k) {
        int r = wavebase + k * 8 + s8;
        rows[k] = r;
        int rc = r < B ? r : B - 1;
        px[k] = cls + (size_t)rc * HDIM + c * 4;
    }

    float acc[8][NW];
#pragma unroll
    for (int k = 0; k < 8; ++k)
#pragma unroll
        for (int w = 0; w < NW; ++w) acc[k][w] = 0.f;

    f32x4 xA[8], xB[8];
#pragma unroll
    for (int k = 0; k < 8; ++k)
        xA[k] = __builtin_nontemporal_load(reinterpret_cast<const f32x4*>(px[k]));

    for (int j = 0; j < 32; j += 2) {
        // prefetch j+1
#pragma unroll
        for (int k = 0; k < 8; ++k)
            xB[k] = __builtin_nontemporal_load(
                reinterpret_cast<const f32x4*>(px[k] + (size_t)(j + 1) * 32));
        // compute j with xA
        {
            const f32x4* wp = &Wl[(j * 8 + c) * NW];
#pragma unroll
            for (int w = 0; w < NW; ++w) {
                f32x4 wf = wp[w];
#pragma unroll
                for (int k = 0; k < 8; ++k) {
                    float a = acc[k][w];
                    a = fmaf(xA[k].x, wf.x, a);
                    a = fmaf(xA[k].y, wf.y, a);
                    a = fmaf(xA[k].z, wf.z, a);
                    a = fmaf(xA[k].w, wf.w, a);
                    acc[k][w] = a;
                }
            }
        }
        // prefetch j+2
        if (j + 2 < 32) {
#pragma unroll
            for (int k = 0; k < 8; ++k)
                xA[k] = __builtin_nontemporal_load(
                    reinterpret_cast<const f32x4*>(px[k] + (size_t)(j + 2) * 32));
        }
        // compute j+1 with xB
        {
            const f32x4* wq = &Wl[((j + 1) * 8 + c) * NW];
#pragma unroll
            for (int w = 0; w < NW; ++w) {
                f32x4 wf = wq[w];
#pragma unroll
                for (int k = 0; k < 8; ++k) {
                    float a = acc[k][w];
                    a = fmaf(xB[k].x, wf.x, a);
                    a = fmaf(xB[k].y, wf.y, a);
                    a = fmaf(xB[k].z, wf.z, a);
                    a = fmaf(xB[k].w, wf.w, a);
                    acc[k][w] = a;
                }
            }
        }
    }

    // ---- Reduce across the 8-lane cluster (c dimension): xor 1,2,4 ----
#pragma unroll
    for (int k = 0; k < 8; ++k)
#pragma unroll
        for (int w = 0; w < NW; ++w) {
            float v = acc[k][w];
            v += __shfl_xor(v, 1);
            v += __shfl_xor(v, 2);
            v += __shfl_xor(v, 4);
            acc[k][w] = v;
        }

    // ---- Per row: gate argmax (strict >, first-max tiebreak) + expert select ----
#pragma unroll
    for (int k = 0; k < 8; ++k) {
        float best = acc[k][0] + gb[0];
        int idx = 0;
#pragma unroll
        for (int e = 1; e < 6; ++e) {
            float v = acc[k][e] + gb[e];
            if (v > best) { best = v; idx = e; }
        }
        float o0 = 0.f, o1 = 0.f;
#pragma unroll
        for (int e = 0; e < 6; ++e) {
            bool m = (idx == e);
            o0 = m ? (acc[k][6 + 2 * e] + eb[2 * e])     : o0;
            o1 = m ? (acc[k][7 + 2 * e] + eb[2 * e + 1]) : o1;
        }
        if (c == 0 && rows[k] < B)
            *reinterpret_cast<float2*>(out + (size_t)rows[k] * 2) = make_float2(o0, o1);
    }
}

extern "C" void kernel_launch(void* const* d_in, const int* in_sizes, int n_in,
                              void* d_out, int out_size, void* d_ws, size_t ws_size,
                              hipStream_t stream) {
    const float* cls      = (const float*)d_in[0];
    const float* gate_w   = (const float*)d_in[1];
    const float* gate_b   = (const float*)d_in[2];
    const float* expert_w = (const float*)d_in[3];
    const float* expert_b = (const float*)d_in[4];
    float* out = (float*)d_out;

    const int B = in_sizes[0] / HDIM;
    const int grid = (B + ROWS_PER_BLOCK - 1) / ROWS_PER_BLOCK;

    hardmoe_kernel<<<grid, NTHREADS, 0, stream>>>(cls, gate_w, gate_b,
                                                  expert_w, expert_b, out, B);
}